// Round 7
// baseline (245.293 us; speedup 1.0000x reference)
//
#include <hip/hip_runtime.h>

#define NN 100000
#define NE 600000
constexpr int FIN = 128;
constexpr int SCAN_BLOCKS = (NN + 255) / 256;  // 391

typedef __attribute__((ext_vector_type(8))) short bf16x8;
typedef __attribute__((ext_vector_type(4))) float f32x4;

// ---------------- helpers ----------------
__device__ __forceinline__ unsigned packbf2(float a, float b) {  // RNE both halves
  unsigned ua = __float_as_uint(a); ua += 0x7FFFu + ((ua >> 16) & 1u);
  unsigned ub = __float_as_uint(b); ub += 0x7FFFu + ((ub >> 16) & 1u);
  return (ua >> 16) | (ub & 0xFFFF0000u);
}
__device__ __forceinline__ float lo16f(unsigned u) { return __uint_as_float(u << 16); }
__device__ __forceinline__ float hi16f(unsigned u) { return __uint_as_float(u & 0xFFFF0000u); }

__device__ __forceinline__ void acc8(float* a, const uint4& v) {
  a[0] += lo16f(v.x); a[1] += hi16f(v.x);
  a[2] += lo16f(v.y); a[3] += hi16f(v.y);
  a[4] += lo16f(v.z); a[5] += hi16f(v.z);
  a[6] += lo16f(v.w); a[7] += hi16f(v.w);
}

// ---------------- utility kernels ----------------

__global__ __launch_bounds__(256) void k_zero(float4* p, int n4) {
  int i = blockIdx.x * blockDim.x + threadIdx.x;
  int st = gridDim.x * blockDim.x;
  for (; i < n4; i += st) p[i] = make_float4(0.f, 0.f, 0.f, 0.f);
}

// fp32 -> bf16 row-major cast (8 elems/thread)
__global__ __launch_bounds__(256) void k_cast(const float* __restrict__ in,
                                              short* __restrict__ outb, int n8) {
  int i = blockIdx.x * blockDim.x + threadIdx.x;
  if (i >= n8) return;
  const float4 v0 = *reinterpret_cast<const float4*>(in + (size_t)i * 8);
  const float4 v1 = *reinterpret_cast<const float4*>(in + (size_t)i * 8 + 4);
  uint4 o;
  o.x = packbf2(v0.x, v0.y);
  o.y = packbf2(v0.z, v0.w);
  o.z = packbf2(v1.x, v1.y);
  o.w = packbf2(v1.z, v1.w);
  *reinterpret_cast<uint4*>(outb + (size_t)i * 8) = o;
}

__global__ __launch_bounds__(256) void k_count(const int* __restrict__ dst,
                                               int* __restrict__ deg) {
  int e = blockIdx.x * blockDim.x + threadIdx.x;
  if (e < NE) {
    int d = dst[e];
    if ((unsigned)d < NN) atomicAdd(&deg[d], 1);
  }
}

// ---------------- CSR build: scan + fill ----------------

// inclusive block scan of deg -> rowptr[i+1] (partial), block sums, inv-degree
__global__ __launch_bounds__(256) void k_scan1(const int* __restrict__ deg,
                                               int* __restrict__ rowptr,
                                               int* __restrict__ bsum,
                                               float* __restrict__ inv) {
  __shared__ int s[256];
  int i = blockIdx.x * 256 + threadIdx.x;
  int v = (i < NN) ? deg[i] : 0;
  s[threadIdx.x] = v;
  if (i < NN) inv[i] = 1.0f / fmaxf((float)v, 1.0f);
  __syncthreads();
#pragma unroll
  for (int off = 1; off < 256; off <<= 1) {
    int t = (threadIdx.x >= off) ? s[threadIdx.x - off] : 0;
    __syncthreads();
    s[threadIdx.x] += t;
    __syncthreads();
  }
  if (i < NN) rowptr[i + 1] = s[threadIdx.x];
  if (threadIdx.x == 255) bsum[blockIdx.x] = s[255];
}

__global__ __launch_bounds__(512) void k_scan2(int* __restrict__ bsum, int nb) {
  __shared__ int s[512];
  int v = (threadIdx.x < nb) ? bsum[threadIdx.x] : 0;
  s[threadIdx.x] = v;
  __syncthreads();
#pragma unroll
  for (int off = 1; off < 512; off <<= 1) {
    int t = (threadIdx.x >= off) ? s[threadIdx.x - off] : 0;
    __syncthreads();
    s[threadIdx.x] += t;
    __syncthreads();
  }
  if (threadIdx.x < nb) bsum[threadIdx.x] = s[threadIdx.x];
}

__global__ __launch_bounds__(256) void k_scan3(const int* __restrict__ bsum,
                                               int* __restrict__ rowptr) {
  int i = blockIdx.x * 256 + threadIdx.x;
  if (i < NN && blockIdx.x > 0) rowptr[i + 1] += bsum[blockIdx.x - 1];
  if (i == 0) rowptr[0] = 0;
}

__global__ __launch_bounds__(256) void k_fill(const int* __restrict__ src,
                                              const int* __restrict__ dst,
                                              const int* __restrict__ rowptr,
                                              int* __restrict__ cursor,
                                              int* __restrict__ adj) {
  int e = blockIdx.x * blockDim.x + threadIdx.x;
  if (e < NE) {
    int d = dst[e];
    int s = src[e];
    if ((unsigned)d < NN && (unsigned)s < NN) {
      int pos = atomicAdd(&cursor[d], 1);
      adj[rowptr[d] + pos] = s;
    }
  }
}

// ---------------- weight pre-cast into per-lane packed fragment order ----
// pidx = (((chunk*NCT + c)*2 + ks)*64 + lane)*8 + t
// value = bf16( W[j=c*16+(lane&15)][k=chunk*64+ks*32+(lane>>4)*8+t] ), W=[Wl|Wr]
template <int FOUT>
__global__ __launch_bounds__(256) void k_castw(const float* __restrict__ Wl,
                                               const float* __restrict__ Wr,
                                               short* __restrict__ wpk) {
  constexpr int NCT = FOUT / 16;
  int pidx = blockIdx.x * 256 + threadIdx.x;
  if (pidx >= FOUT * 256) return;
  int t = pidx & 7;
  int lane = (pidx >> 3) & 63;
  int ks = (pidx >> 9) & 1;
  int c = (pidx >> 10) & (NCT - 1);
  int chunk = pidx >> (10 + (NCT == 8 ? 3 : 2));
  int l15 = lane & 15, lq = lane >> 4;
  int j = c * 16 + l15;
  int k = chunk * 64 + ks * 32 + lq * 8 + t;
  float v = (k < 128) ? Wl[j * 128 + k] : Wr[j * 128 + (k - 128)];
  unsigned u = __float_as_uint(v);
  u += 0x7FFFu + ((u >> 16) & 1u);
  wpk[pidx] = (short)(u >> 16);
}

// ---------------- fused gather(bf16) + MFMA GEMM (bf16 activations) ------
// 128-thr block = 2 waves; wave owns 16 rows. Phase 1: quarter-wave per node,
// 2-node pair-interleaved edge loops (4 rows in flight), metadata hoisted,
// self-term prefetched. Phase 2: single-bf16 MFMA, K=256 = [mean | h].
// No barriers anywhere.
template <int FOUT, bool RELU, bool WF32, bool WB16>
__global__ __launch_bounds__(128, 4) void k_fused(
    const int* __restrict__ rowptr, const int* __restrict__ adj,
    const short* __restrict__ hb, const float* __restrict__ inv,
    const short* __restrict__ wpk, const float* __restrict__ bias,
    float* __restrict__ out, short* __restrict__ outb) {
  constexpr int NCT = FOUT / 16;
  constexpr int LSTR = 136;  // shorts; 272 B rows
  __shared__ short lds[2][16 * LSTR];
  const int lane = threadIdx.x & 63;
  const int w = threadIdx.x >> 6;
  const int l15 = lane & 15;
  const int lq = lane >> 4;  // quarter id (phase 1) / k-octet (phase 2)
  const int n0 = blockIdx.x * 32 + w * 16;
  short* myLds = lds[w];

  const int row = n0 + l15;
  const bool rok = (row < NN);

  // ---- prefetch self-term rows (independent of gather) ----
  bf16x8 selfa[4];
  {
    const short* sp = hb + (size_t)row * FIN + lq * 8;
#pragma unroll
    for (int q = 0; q < 4; ++q) {
      if (rok) {
        selfa[q] = *reinterpret_cast<const bf16x8*>(sp + (q >> 1) * 64 + (q & 1) * 32);
      } else {
#pragma unroll
        for (int i = 0; i < 8; ++i) selfa[q][i] = 0;
      }
    }
  }

  // ---- hoist metadata for this quarter's 4 nodes ----
  int begs[4], ends[4];
  float invs[4];
#pragma unroll
  for (int i = 0; i < 4; ++i) {
    const int nd = n0 + 4 * i + lq;
    const bool ok = nd < NN;
    begs[i] = ok ? rowptr[nd] : 0;
    ends[i] = ok ? rowptr[nd + 1] : 0;
    invs[i] = ok ? inv[nd] : 0.f;
  }

  // ---- phase 1: pair-interleaved gather; lane covers 8 bf16 (16 B) ----
#pragma unroll
  for (int p = 0; p < 2; ++p) {
    const int iA = 2 * p, iB = 2 * p + 1;
    float aA[8] = {0.f, 0.f, 0.f, 0.f, 0.f, 0.f, 0.f, 0.f};
    float aB[8] = {0.f, 0.f, 0.f, 0.f, 0.f, 0.f, 0.f, 0.f};
    int eA = begs[iA], eB = begs[iB];
    const int endA = ends[iA], endB = ends[iB];
    // joint loop: 4 independent row loads in flight
    while (eA + 1 < endA && eB + 1 < endB) {
      int sa0 = adj[eA], sa1 = adj[eA + 1];
      int sb0 = adj[eB], sb1 = adj[eB + 1];
      uint4 vA0 = *reinterpret_cast<const uint4*>(hb + (size_t)sa0 * FIN + l15 * 8);
      uint4 vA1 = *reinterpret_cast<const uint4*>(hb + (size_t)sa1 * FIN + l15 * 8);
      uint4 vB0 = *reinterpret_cast<const uint4*>(hb + (size_t)sb0 * FIN + l15 * 8);
      uint4 vB1 = *reinterpret_cast<const uint4*>(hb + (size_t)sb1 * FIN + l15 * 8);
      acc8(aA, vA0); acc8(aA, vA1);
      acc8(aB, vB0); acc8(aB, vB1);
      eA += 2; eB += 2;
    }
    // tails (2-deep)
    for (; eA + 1 < endA; eA += 2) {
      int s0 = adj[eA], s1 = adj[eA + 1];
      uint4 v0 = *reinterpret_cast<const uint4*>(hb + (size_t)s0 * FIN + l15 * 8);
      uint4 v1 = *reinterpret_cast<const uint4*>(hb + (size_t)s1 * FIN + l15 * 8);
      acc8(aA, v0); acc8(aA, v1);
    }
    if (eA < endA) {
      uint4 v0 = *reinterpret_cast<const uint4*>(hb + (size_t)adj[eA] * FIN + l15 * 8);
      acc8(aA, v0);
    }
    for (; eB + 1 < endB; eB += 2) {
      int s0 = adj[eB], s1 = adj[eB + 1];
      uint4 v0 = *reinterpret_cast<const uint4*>(hb + (size_t)s0 * FIN + l15 * 8);
      uint4 v1 = *reinterpret_cast<const uint4*>(hb + (size_t)s1 * FIN + l15 * 8);
      acc8(aB, v0); acc8(aB, v1);
    }
    if (eB < endB) {
      uint4 v0 = *reinterpret_cast<const uint4*>(hb + (size_t)adj[eB] * FIN + l15 * 8);
      acc8(aB, v0);
    }
    // store means to wave-private LDS
    {
      const float s = invs[iA];
      uint4 o;
      o.x = packbf2(aA[0] * s, aA[1] * s);
      o.y = packbf2(aA[2] * s, aA[3] * s);
      o.z = packbf2(aA[4] * s, aA[5] * s);
      o.w = packbf2(aA[6] * s, aA[7] * s);
      *reinterpret_cast<uint4*>(&myLds[(4 * iA + lq) * LSTR + l15 * 8]) = o;
    }
    {
      const float s = invs[iB];
      uint4 o;
      o.x = packbf2(aB[0] * s, aB[1] * s);
      o.y = packbf2(aB[2] * s, aB[3] * s);
      o.z = packbf2(aB[4] * s, aB[5] * s);
      o.w = packbf2(aB[6] * s, aB[7] * s);
      *reinterpret_cast<uint4*>(&myLds[(4 * iB + lq) * LSTR + l15 * 8]) = o;
    }
  }

  // ---- phase 2: MFMA over 4 K-chunks of 64 (single bf16 A) ----
  f32x4 acc[NCT];
#pragma unroll
  for (int c = 0; c < NCT; ++c)
#pragma unroll
    for (int q = 0; q < 4; ++q) acc[c][q] = 0.f;

#pragma unroll
  for (int chunk = 0; chunk < 4; ++chunk) {
    bf16x8 a[2];
    if (chunk < 2) {
#pragma unroll
      for (int ks = 0; ks < 2; ++ks)
        a[ks] = *reinterpret_cast<const bf16x8*>(
            &myLds[l15 * LSTR + chunk * 64 + ks * 32 + lq * 8]);
    } else {
      a[0] = selfa[(chunk - 2) * 2 + 0];
      a[1] = selfa[(chunk - 2) * 2 + 1];
    }
#pragma unroll
    for (int c = 0; c < NCT; ++c) {
#pragma unroll
      for (int ks = 0; ks < 2; ++ks) {
        bf16x8 b = *reinterpret_cast<const bf16x8*>(
            wpk + ((size_t)(((chunk * NCT + c) * 2 + ks) * 64 + lane)) * 8);
        acc[c] = __builtin_amdgcn_mfma_f32_16x16x32_bf16(b, a[ks], acc[c], 0, 0, 0);
      }
    }
  }

  // ---- epilogue: bias (+relu); bf16 shadow and/or fp32 stores ----
#pragma unroll
  for (int c = 0; c < NCT; ++c) {
    const f32x4 bb = *reinterpret_cast<const f32x4*>(bias + c * 16 + lq * 4);
    if (rok) {
      f32x4 v = acc[c] + bb;
      if (RELU) {
#pragma unroll
        for (int q = 0; q < 4; ++q) v[q] = fmaxf(v[q], 0.f);
      }
      if (WF32)
        *reinterpret_cast<f32x4*>(out + (size_t)row * FOUT + c * 16 + lq * 4) = v;
      if (WB16) {
        uint2 o;
        o.x = packbf2(v[0], v[1]);
        o.y = packbf2(v[2], v[3]);
        *reinterpret_cast<uint2*>(outb + (size_t)row * FOUT + c * 16 + lq * 4) = o;
      }
    }
  }
}

// ---------------- launch ----------------

static inline size_t align512(size_t x) { return (x + 511) & ~(size_t)511; }

extern "C" void kernel_launch(void* const* d_in, const int* in_sizes, int n_in,
                              void* d_out, int out_size, void* d_ws, size_t ws_size,
                              hipStream_t stream) {
  const float* x   = (const float*)d_in[0];
  const int*   ei  = (const int*)d_in[1];
  const float* Wl0 = (const float*)d_in[2];
  const float* bl0 = (const float*)d_in[3];
  const float* Wr0 = (const float*)d_in[4];
  const float* Wl1 = (const float*)d_in[5];
  const float* bl1 = (const float*)d_in[6];
  const float* Wr1 = (const float*)d_in[7];
  const float* Wl2 = (const float*)d_in[8];
  const float* bl2 = (const float*)d_in[9];
  const float* Wr2 = (const float*)d_in[10];
  float* out = (float*)d_out;

  char* ws = (char*)d_ws;
  size_t off = 0;
  float* inv    = (float*)(ws + off); off = align512(off + (size_t)NN * 4);
  short* xb     = (short*)(ws + off); off = align512(off + (size_t)NN * FIN * 2);
  short* hb1    = (short*)(ws + off); off = align512(off + (size_t)NN * FIN * 2);
  short* hb2    = (short*)(ws + off); off = align512(off + (size_t)NN * FIN * 2);
  short* wpk0   = (short*)(ws + off); off = align512(off + (size_t)128 * 256 * 2);
  short* wpk1   = (short*)(ws + off); off = align512(off + (size_t)128 * 256 * 2);
  short* wpk2   = (short*)(ws + off); off = align512(off + (size_t)64 * 256 * 2);
  int*   deg    = (int*)(ws + off);   // deg + cursor adjacent: zeroed in one call
  int*   cursor = deg + NN;           off = align512(off + (size_t)2 * NN * 4);
  int*   rowptr = (int*)(ws + off);   off = align512(off + (size_t)(NN + 1) * 4);
  int*   bsum   = (int*)(ws + off);   off = align512(off + (size_t)SCAN_BLOCKS * 4);
  int*   adj    = (int*)(ws + off);   off = align512(off + (size_t)NE * 4);

  const int* srcp = ei;
  const int* dstp = ei + NE;

  const int fused_blocks = (NN + 31) / 32;             // 3125
  const int cast_blocks = (NN * FIN / 8 + 255) / 256;  // 6250

  // ---- weight pre-cast + x bf16 shadow (independent of graph) ----
  k_castw<128><<<128, 256, 0, stream>>>(Wl0, Wr0, wpk0);
  k_castw<128><<<128, 256, 0, stream>>>(Wl1, Wr1, wpk1);
  k_castw<64><<<64, 256, 0, stream>>>(Wl2, Wr2, wpk2);
  k_cast<<<cast_blocks, 256, 0, stream>>>(x, xb, NN * FIN / 8);

  // ---- CSR build (once; graph shared across layers) ----
  k_zero<<<128, 256, 0, stream>>>((float4*)deg, 2 * NN / 4);
  k_count<<<(NE + 255) / 256, 256, 0, stream>>>(dstp, deg);
  k_scan1<<<SCAN_BLOCKS, 256, 0, stream>>>(deg, rowptr, bsum, inv);
  k_scan2<<<1, 512, 0, stream>>>(bsum, SCAN_BLOCKS);
  k_scan3<<<SCAN_BLOCKS, 256, 0, stream>>>(bsum, rowptr);
  k_fill<<<(NE + 255) / 256, 256, 0, stream>>>(srcp, dstp, rowptr, cursor, adj);

  // ---- 3 fused layers (bf16 activations end-to-end) ----
  k_fused<128, true, false, true><<<fused_blocks, 128, 0, stream>>>(
      rowptr, adj, xb, inv, wpk0, bl0, nullptr, hb1);
  k_fused<128, true, false, true><<<fused_blocks, 128, 0, stream>>>(
      rowptr, adj, hb1, inv, wpk1, bl1, nullptr, hb2);
  k_fused<64, false, true, false><<<fused_blocks, 128, 0, stream>>>(
      rowptr, adj, hb2, inv, wpk2, bl2, out, nullptr);
}

// Round 8
// 223.830 us; speedup vs baseline: 1.0959x; 1.0959x over previous
//
#include <hip/hip_runtime.h>

#define NN 100000
#define NE 600000
constexpr int FIN = 128;
constexpr int SCAN_BLOCKS = (NN + 255) / 256;  // 391

typedef __attribute__((ext_vector_type(8))) short bf16x8;
typedef __attribute__((ext_vector_type(4))) float f32x4;

// ---------------- helpers ----------------
__device__ __forceinline__ unsigned packbf2(float a, float b) {  // RNE both halves
  unsigned ua = __float_as_uint(a); ua += 0x7FFFu + ((ua >> 16) & 1u);
  unsigned ub = __float_as_uint(b); ub += 0x7FFFu + ((ub >> 16) & 1u);
  return (ua >> 16) | (ub & 0xFFFF0000u);
}
__device__ __forceinline__ float lo16f(unsigned u) { return __uint_as_float(u << 16); }
__device__ __forceinline__ float hi16f(unsigned u) { return __uint_as_float(u & 0xFFFF0000u); }

__device__ __forceinline__ void acc8(float* a, const uint4& v) {
  a[0] += lo16f(v.x); a[1] += hi16f(v.x);
  a[2] += lo16f(v.y); a[3] += hi16f(v.y);
  a[4] += lo16f(v.z); a[5] += hi16f(v.z);
  a[6] += lo16f(v.w); a[7] += hi16f(v.w);
}

// weight pack decode: pidx = (((chunk*NCT + c)*2 + ks)*64 + lane)*8 + t
// value = bf16( W[j=c*16+(lane&15)][k=chunk*64+ks*32+(lane>>4)*8+t] ), W=[Wl|Wr]
template <int NCT>
__device__ __forceinline__ void castw_one(int pidx, const float* __restrict__ Wl,
                                          const float* __restrict__ Wr,
                                          short* __restrict__ wpk) {
  int t = pidx & 7;
  int lane = (pidx >> 3) & 63;
  int ks = (pidx >> 9) & 1;
  int c = (pidx >> 10) & (NCT - 1);
  int chunk = pidx >> ((NCT == 8) ? 13 : 12);
  int l15 = lane & 15, lq = lane >> 4;
  int j = c * 16 + l15;
  int k = chunk * 64 + ks * 32 + lq * 8 + t;
  float v = (k < 128) ? Wl[j * 128 + k] : Wr[j * 128 + (k - 128)];
  unsigned u = __float_as_uint(v);
  u += 0x7FFFu + ((u >> 16) & 1u);
  wpk[pidx] = (short)(u >> 16);
}

// ---------------- combined prep kernel ----------------
// blocks [0,320): pack all 3 layers' weights into wpk_all (contiguous)
// blocks [320,516): zero deg+cursor (2*NN ints)
// blocks [516,6766): cast x -> xb (bf16)
__global__ __launch_bounds__(256) void k_prep(
    const float* __restrict__ Wl0, const float* __restrict__ Wr0,
    const float* __restrict__ Wl1, const float* __restrict__ Wr1,
    const float* __restrict__ Wl2, const float* __restrict__ Wr2,
    short* __restrict__ wpk_all, float4* __restrict__ dc,
    const float* __restrict__ x, short* __restrict__ xb) {
  const int b = blockIdx.x;
  if (b < 320) {
    int pidx = b * 256 + threadIdx.x;  // [0, 81920)
    if (pidx < 32768) castw_one<8>(pidx, Wl0, Wr0, wpk_all);
    else if (pidx < 65536) castw_one<8>(pidx - 32768, Wl1, Wr1, wpk_all + 32768);
    else castw_one<4>(pidx - 65536, Wl2, Wr2, wpk_all + 65536);
  } else if (b < 516) {
    int i = (b - 320) * 256 + threadIdx.x;  // float4 over 2*NN ints
    if (i < 2 * NN / 4) dc[i] = make_float4(0.f, 0.f, 0.f, 0.f);
  } else {
    int i = (b - 516) * 256 + threadIdx.x;  // 8 elems each, NN*FIN/8 total
    if (i < NN * FIN / 8) {
      const float4 v0 = *reinterpret_cast<const float4*>(x + (size_t)i * 8);
      const float4 v1 = *reinterpret_cast<const float4*>(x + (size_t)i * 8 + 4);
      uint4 o;
      o.x = packbf2(v0.x, v0.y);
      o.y = packbf2(v0.z, v0.w);
      o.z = packbf2(v1.x, v1.y);
      o.w = packbf2(v1.z, v1.w);
      *reinterpret_cast<uint4*>(xb + (size_t)i * 8) = o;
    }
  }
}

// ---------------- CSR build ----------------

__global__ __launch_bounds__(256) void k_count(const int* __restrict__ dst,
                                               int* __restrict__ deg) {
  int e = blockIdx.x * blockDim.x + threadIdx.x;
  if (e < NE) {
    int d = dst[e];
    if ((unsigned)d < NN) atomicAdd(&deg[d], 1);
  }
}

// inclusive block scan of deg -> rowptr[i+1] (partial), block sums, inv-degree
__global__ __launch_bounds__(256) void k_scan1(const int* __restrict__ deg,
                                               int* __restrict__ rowptr,
                                               int* __restrict__ bsum,
                                               float* __restrict__ inv) {
  __shared__ int s[256];
  int i = blockIdx.x * 256 + threadIdx.x;
  int v = (i < NN) ? deg[i] : 0;
  s[threadIdx.x] = v;
  if (i < NN) inv[i] = 1.0f / fmaxf((float)v, 1.0f);
  __syncthreads();
#pragma unroll
  for (int off = 1; off < 256; off <<= 1) {
    int t = (threadIdx.x >= off) ? s[threadIdx.x - off] : 0;
    __syncthreads();
    s[threadIdx.x] += t;
    __syncthreads();
  }
  if (i < NN) rowptr[i + 1] = s[threadIdx.x];
  if (threadIdx.x == 255) bsum[blockIdx.x] = s[255];
}

__global__ __launch_bounds__(512) void k_scan2(int* __restrict__ bsum, int nb) {
  __shared__ int s[512];
  int v = (threadIdx.x < nb) ? bsum[threadIdx.x] : 0;
  s[threadIdx.x] = v;
  __syncthreads();
#pragma unroll
  for (int off = 1; off < 512; off <<= 1) {
    int t = (threadIdx.x >= off) ? s[threadIdx.x - off] : 0;
    __syncthreads();
    s[threadIdx.x] += t;
    __syncthreads();
  }
  if (threadIdx.x < nb) bsum[threadIdx.x] = s[threadIdx.x];
}

__global__ __launch_bounds__(256) void k_scan3(const int* __restrict__ bsum,
                                               int* __restrict__ rowptr) {
  int i = blockIdx.x * 256 + threadIdx.x;
  if (i < NN && blockIdx.x > 0) rowptr[i + 1] += bsum[blockIdx.x - 1];
  if (i == 0) rowptr[0] = 0;
}

__global__ __launch_bounds__(256) void k_fill(const int* __restrict__ src,
                                              const int* __restrict__ dst,
                                              const int* __restrict__ rowptr,
                                              int* __restrict__ cursor,
                                              int* __restrict__ adj) {
  int e = blockIdx.x * blockDim.x + threadIdx.x;
  if (e < NE) {
    int d = dst[e];
    int s = src[e];
    if ((unsigned)d < NN && (unsigned)s < NN) {
      int pos = atomicAdd(&cursor[d], 1);
      adj[rowptr[d] + pos] = s;
    }
  }
}

// ---------------- standalone gather: quarter-wave per node ----------------
// 16 lanes x 16 B = one 256-B bf16 row; 4-deep edge unroll; mean -> mb (bf16)
__global__ __launch_bounds__(256, 8) void k_gather2(
    const int* __restrict__ rowptr, const int* __restrict__ adj,
    const short* __restrict__ hb, const float* __restrict__ inv,
    short* __restrict__ mb) {
  const int node = blockIdx.x * 16 + (threadIdx.x >> 4);
  const int l15 = threadIdx.x & 15;
  if (node >= NN) return;
  const int beg = rowptr[node];
  const int end = rowptr[node + 1];
  const float s = inv[node];
  float a[8] = {0.f, 0.f, 0.f, 0.f, 0.f, 0.f, 0.f, 0.f};
  int e = beg;
  for (; e + 3 < end; e += 4) {
    int s0 = adj[e], s1 = adj[e + 1], s2 = adj[e + 2], s3 = adj[e + 3];
    uint4 v0 = *reinterpret_cast<const uint4*>(hb + (size_t)s0 * FIN + l15 * 8);
    uint4 v1 = *reinterpret_cast<const uint4*>(hb + (size_t)s1 * FIN + l15 * 8);
    uint4 v2 = *reinterpret_cast<const uint4*>(hb + (size_t)s2 * FIN + l15 * 8);
    uint4 v3 = *reinterpret_cast<const uint4*>(hb + (size_t)s3 * FIN + l15 * 8);
    acc8(a, v0); acc8(a, v1); acc8(a, v2); acc8(a, v3);
  }
  for (; e < end; ++e) {
    uint4 v = *reinterpret_cast<const uint4*>(hb + (size_t)adj[e] * FIN + l15 * 8);
    acc8(a, v);
  }
  uint4 o;
  o.x = packbf2(a[0] * s, a[1] * s);
  o.y = packbf2(a[2] * s, a[3] * s);
  o.z = packbf2(a[4] * s, a[5] * s);
  o.w = packbf2(a[6] * s, a[7] * s);
  *reinterpret_cast<uint4*>(mb + (size_t)node * FIN + l15 * 8) = o;
}

// ---------------- streaming MFMA GEMM, LDS-staged weights ----------------
// 512-thr block = 8 waves, 128 rows. Weights staged once to LDS (1 barrier);
// A-fragments (mean from mb, self from hb) hoisted before the barrier.
template <int FOUT, bool RELU, bool WF32, bool WB16>
__global__ __launch_bounds__(512, 2) void k_gemm2(
    const short* __restrict__ hb, const short* __restrict__ mb,
    const short* __restrict__ wpk, const float* __restrict__ bias,
    float* __restrict__ out, short* __restrict__ outb) {
  constexpr int NCT = FOUT / 16;
  constexpr int NFR = NCT * 4 * 2;       // weight fragments (64 or 32)
  __shared__ short wlds[NFR * 64 * 8];   // 64 KB or 32 KB
  const int lane = threadIdx.x & 63;
  const int w = threadIdx.x >> 6;
  const int l15 = lane & 15;
  const int lq = lane >> 4;
  const int n0 = (blockIdx.x * 8 + w) * 16;
  const int row = n0 + l15;
  const bool ok = row < NN;

  // stage weights cooperatively (uint4 strided, coalesced)
#pragma unroll
  for (int i = 0; i < NFR / 8; ++i) {
    int idx = i * 512 + threadIdx.x;  // uint4 index over NFR*64*16B
    reinterpret_cast<uint4*>(wlds)[idx] =
        reinterpret_cast<const uint4*>(wpk)[idx];
  }

  // hoist A fragments (global loads overlap the staging)
  bf16x8 am[4], as_[4];
  {
    const short* mp = mb + (size_t)row * FIN + lq * 8;
    const short* sp = hb + (size_t)row * FIN + lq * 8;
#pragma unroll
    for (int q = 0; q < 4; ++q) {
      const int o = (q >> 1) * 64 + (q & 1) * 32;
      if (ok) {
        am[q] = *reinterpret_cast<const bf16x8*>(mp + o);
        as_[q] = *reinterpret_cast<const bf16x8*>(sp + o);
      } else {
#pragma unroll
        for (int i = 0; i < 8; ++i) { am[q][i] = 0; as_[q][i] = 0; }
      }
    }
  }

  __syncthreads();

  f32x4 acc[NCT];
#pragma unroll
  for (int c = 0; c < NCT; ++c)
#pragma unroll
    for (int q = 0; q < 4; ++q) acc[c][q] = 0.f;

#pragma unroll
  for (int chunk = 0; chunk < 4; ++chunk) {
    const bf16x8 a0 = (chunk < 2) ? am[chunk * 2 + 0] : as_[(chunk - 2) * 2 + 0];
    const bf16x8 a1 = (chunk < 2) ? am[chunk * 2 + 1] : as_[(chunk - 2) * 2 + 1];
#pragma unroll
    for (int c = 0; c < NCT; ++c) {
      const bf16x8 b0 = *reinterpret_cast<const bf16x8*>(
          &wlds[(((chunk * NCT + c) * 2 + 0) * 64 + lane) * 8]);
      const bf16x8 b1 = *reinterpret_cast<const bf16x8*>(
          &wlds[(((chunk * NCT + c) * 2 + 1) * 64 + lane) * 8]);
      acc[c] = __builtin_amdgcn_mfma_f32_16x16x32_bf16(b0, a0, acc[c], 0, 0, 0);
      acc[c] = __builtin_amdgcn_mfma_f32_16x16x32_bf16(b1, a1, acc[c], 0, 0, 0);
    }
  }

  // epilogue: bias (+relu); fp32 and/or bf16 stores
#pragma unroll
  for (int c = 0; c < NCT; ++c) {
    const f32x4 bb = *reinterpret_cast<const f32x4*>(bias + c * 16 + lq * 4);
    if (ok) {
      f32x4 v = acc[c] + bb;
      if (RELU) {
#pragma unroll
        for (int q = 0; q < 4; ++q) v[q] = fmaxf(v[q], 0.f);
      }
      if (WF32)
        *reinterpret_cast<f32x4*>(out + (size_t)row * FOUT + c * 16 + lq * 4) = v;
      if (WB16) {
        uint2 o;
        o.x = packbf2(v[0], v[1]);
        o.y = packbf2(v[2], v[3]);
        *reinterpret_cast<uint2*>(outb + (size_t)row * FOUT + c * 16 + lq * 4) = o;
      }
    }
  }
}

// ---------------- launch ----------------

static inline size_t align512(size_t x) { return (x + 511) & ~(size_t)511; }

extern "C" void kernel_launch(void* const* d_in, const int* in_sizes, int n_in,
                              void* d_out, int out_size, void* d_ws, size_t ws_size,
                              hipStream_t stream) {
  const float* x   = (const float*)d_in[0];
  const int*   ei  = (const int*)d_in[1];
  const float* Wl0 = (const float*)d_in[2];
  const float* bl0 = (const float*)d_in[3];
  const float* Wr0 = (const float*)d_in[4];
  const float* Wl1 = (const float*)d_in[5];
  const float* bl1 = (const float*)d_in[6];
  const float* Wr1 = (const float*)d_in[7];
  const float* Wl2 = (const float*)d_in[8];
  const float* bl2 = (const float*)d_in[9];
  const float* Wr2 = (const float*)d_in[10];
  float* out = (float*)d_out;

  char* ws = (char*)d_ws;
  size_t off = 0;
  float* inv     = (float*)(ws + off); off = align512(off + (size_t)NN * 4);
  short* xb      = (short*)(ws + off); off = align512(off + (size_t)NN * FIN * 2);
  short* hb1     = (short*)(ws + off); off = align512(off + (size_t)NN * FIN * 2);
  short* hb2     = (short*)(ws + off); off = align512(off + (size_t)NN * FIN * 2);
  short* mb      = (short*)(ws + off); off = align512(off + (size_t)NN * FIN * 2);
  short* wpk_all = (short*)(ws + off); off = align512(off + (size_t)(32768 + 32768 + 16384) * 2);
  int*   deg     = (int*)(ws + off);   // deg + cursor adjacent: zeroed together
  int*   cursor  = deg + NN;           off = align512(off + (size_t)2 * NN * 4);
  int*   rowptr  = (int*)(ws + off);   off = align512(off + (size_t)(NN + 1) * 4);
  int*   bsum    = (int*)(ws + off);   off = align512(off + (size_t)SCAN_BLOCKS * 4);
  int*   adj     = (int*)(ws + off);   off = align512(off + (size_t)NE * 4);

  short* wpk0 = wpk_all;
  short* wpk1 = wpk_all + 32768;
  short* wpk2 = wpk_all + 65536;

  const int* srcp = ei;
  const int* dstp = ei + NE;

  const int gather_blocks = (NN + 15) / 16;  // 6250
  const int gemm_blocks = (NN + 127) / 128;  // 782
  const int prep_blocks = 320 + 196 + 6250;  // 6766

  // ---- prep: weight packs + deg/cursor zero + x->bf16 (one kernel) ----
  k_prep<<<prep_blocks, 256, 0, stream>>>(Wl0, Wr0, Wl1, Wr1, Wl2, Wr2,
                                          wpk_all, (float4*)deg, x, xb);

  // ---- CSR build (graph shared across layers) ----
  k_count<<<(NE + 255) / 256, 256, 0, stream>>>(dstp, deg);
  k_scan1<<<SCAN_BLOCKS, 256, 0, stream>>>(deg, rowptr, bsum, inv);
  k_scan2<<<1, 512, 0, stream>>>(bsum, SCAN_BLOCKS);
  k_scan3<<<SCAN_BLOCKS, 256, 0, stream>>>(bsum, rowptr);
  k_fill<<<(NE + 255) / 256, 256, 0, stream>>>(srcp, dstp, rowptr, cursor, adj);

  // ---- 3 layers: gather (mean -> mb) then streaming MFMA GEMM ----
  k_gather2<<<gather_blocks, 256, 0, stream>>>(rowptr, adj, xb, inv, mb);
  k_gemm2<128, true, false, true><<<gemm_blocks, 512, 0, stream>>>(
      xb, mb, wpk0, bl0, nullptr, hb1);

  k_gather2<<<gather_blocks, 256, 0, stream>>>(rowptr, adj, hb1, inv, mb);
  k_gemm2<128, true, false, true><<<gemm_blocks, 512, 0, stream>>>(
      hb1, mb, wpk1, bl1, nullptr, hb2);

  k_gather2<<<gather_blocks, 256, 0, stream>>>(rowptr, adj, hb2, inv, mb);
  k_gemm2<64, false, true, false><<<gemm_blocks, 512, 0, stream>>>(
      hb2, mb, wpk2, bl2, out, nullptr);
}